// Round 7
// baseline (435.928 us; speedup 1.0000x reference)
//
#include <hip/hip_runtime.h>
#include <hip/hip_bf16.h>
#include <cstdint>
#include <cstddef>

#define B_ 4
#define S_ 1024
#define V_ 32000
#define D_ 256
#define H_ 8
#define DH_ 32
#define L_ 4
#define MROWS (B_*S_)

typedef __attribute__((ext_vector_type(8))) short bf16x8;
typedef __attribute__((ext_vector_type(4))) float f32x4;

__device__ __forceinline__ unsigned short f2bf(float f) {
  union { float f; unsigned u; } c; c.f = f;
  unsigned u = c.u;
  u += 0x7fff + ((u >> 16) & 1);   // round-to-nearest-even
  return (unsigned short)(u >> 16);
}
__device__ __forceinline__ float bf2f(unsigned short u) {
  union { unsigned u; float f; } c; c.u = ((unsigned)u) << 16; return c.f;
}

// async global->LDS, 16B per lane; LDS dest is wave-uniform base + lane*16
__device__ __forceinline__ void gload16(const unsigned short* g, unsigned short* l) {
  __builtin_amdgcn_global_load_lds(
      (const __attribute__((address_space(1))) void*)g,
      (__attribute__((address_space(3))) void*)l, 16, 0, 0);
}

// ---- XOR-swizzled LDS tiles (T2): lds[row][inner ^ ((row&7)<<4)] = g[row][inner]
// LDS dest stays LINEAR (gload_lds writes base+lane*16); the global SOURCE is
// inverse-swizzled per lane (XOR of byte bits 4-6 stays inside the row's
// 128B segment -> coalesced). Reads apply the same XOR.
template<int BM, int BK, int NW>
__device__ __forceinline__ void stage_tile_swz(const unsigned short* __restrict__ g, int ldg,
                                               unsigned short* lds, int wave, int lane) {
  constexpr int CH  = BM * BK * 2 / 1024;   // 1KB chunks
  constexpr int BKB = BK * 2;               // bytes per row
#pragma unroll
  for (int t = 0; t < CH / NW; ++t) {
    int c = wave + t * NW;
    int byte  = c * 1024 + lane * 16;
    int row   = byte / BKB;
    int inner = (byte % BKB) ^ ((row & 7) << 4);
    gload16(g + (size_t)row * ldg + (inner >> 1), lds + c * 512);
  }
}

// swizzled 16B fragment read: row-major [*][BKB/2] tile, kbytes multiple of 16
template<int BKB>
__device__ __forceinline__ bf16x8 lds_frag(const unsigned short* base, int row, int kbytes) {
  int b = (row * BKB + kbytes) ^ ((row & 7) << 4);
  return *(const bf16x8*)((const char*)base + b);
}

// ---------------- embed + LN(layer0) + dual-layout emit ----------------
__global__ __launch_bounds__(512) void k_embln(
    const int* __restrict__ X, const float* __restrict__ emb,
    const float* __restrict__ lng, const float* __restrict__ lnb,
    float* __restrict__ x, unsigned short* __restrict__ xbf,
    unsigned short* __restrict__ xnT) {
  __shared__ __align__(16) float xf[16][264];
  __shared__ float mrow[16], rrow[16];
  int r0 = blockIdx.x * 16;
  int tid = threadIdx.x;
  int w = tid >> 6, lane = tid & 63;
#pragma unroll
  for (int rr = 0; rr < 2; rr++) {
    int row = w * 2 + rr; int grow = r0 + row;
    int tok = X[grow];
    f32x4 v = *(const f32x4*)(emb + (size_t)tok * D_ + lane * 4);
    *(f32x4*)(x + (size_t)grow * D_ + lane * 4) = v;
    *(f32x4*)&xf[row][lane * 4] = v;
    float s = v[0] + v[1] + v[2] + v[3];
    float ss = v[0]*v[0] + v[1]*v[1] + v[2]*v[2] + v[3]*v[3];
#pragma unroll
    for (int off = 1; off < 64; off <<= 1) {
      s  += __shfl_xor(s, off, 64);
      ss += __shfl_xor(ss, off, 64);
    }
    float mean = s * (1.f / D_);
    float var = ss * (1.f / D_) - mean * mean;
    float rinv = rsqrtf(var + 1e-5f);
    float4 g4 = *(const float4*)(lng + lane * 4);
    float4 b4 = *(const float4*)(lnb + lane * 4);
    ushort4 o;
    o.x = f2bf((v[0] - mean) * rinv * g4.x + b4.x);
    o.y = f2bf((v[1] - mean) * rinv * g4.y + b4.y);
    o.z = f2bf((v[2] - mean) * rinv * g4.z + b4.z);
    o.w = f2bf((v[3] - mean) * rinv * g4.w + b4.w);
    *(ushort4*)(xbf + (size_t)grow * D_ + lane * 4) = o;
    if (lane == 0) { mrow[row] = mean; rrow[row] = rinv; }
  }
  __syncthreads();
  int d = tid & 255, half = tid >> 8;
  float gd = lng[d], bd = lnb[d];
  int bb = r0 >> 10, s0 = r0 & 1023;
  bf16x8 o8;
#pragma unroll
  for (int k = 0; k < 8; k++) {
    int srow = half * 8 + k;
    o8[k] = (short)f2bf((xf[srow][d] - mrow[srow]) * rrow[srow] * gd + bd);
  }
  *(bf16x8*)(xnT + ((size_t)(bb * 256 + d)) * S_ + s0 + half * 8) = o8;
}

// ---------------- MFMA attention ----------------
__global__ __launch_bounds__(512) void k_attn2(
    const unsigned short* __restrict__ xbf,   // [4096][256] bf16
    const unsigned short* __restrict__ xnT,   // [4][256][1024] bf16
    const float* __restrict__ WQ, const float* __restrict__ WK,
    const float* __restrict__ WV, const float* __restrict__ Om,
    unsigned short* __restrict__ y, int layer) {
  int b = blockIdx.x >> 6;
  int q0 = (blockIdx.x & 63) << 4;
  int tid = threadIdx.x;
  int w = tid >> 6, l = tid & 63;
  int lr = l & 15, lg = l >> 4;
  int h = w;

  __shared__ __align__(16) unsigned short P_lds[8][16][72];

  const float scale = 0.17677669529663687f;  // 1/sqrt(32)

  bf16x8 aq;
  {
    bf16x8 xq = *(const bf16x8*)(xbf + ((size_t)(b * S_ + q0 + lr)) * D_ + h * DH_ + lg * 8);
#pragma unroll
    for (int j = 0; j < 8; j++) {
      int dj = lg * 8 + j;
      float wq = WQ[((size_t)(layer * H_ + h)) * 1024 + dj * 33];
      float wk = WK[((size_t)(layer * H_ + h)) * 1024 + dj * 33];
      aq[j] = (short)f2bf(bf2f((unsigned short)xq[j]) * wq * wk * scale);
    }
  }
  float dvo[2];
#pragma unroll
  for (int fs = 0; fs < 2; fs++) {
    int fh = fs * 16 + lr;
    int fc = h * DH_ + fh;
    dvo[fs] = WV[((size_t)(layer * H_ + h)) * 1024 + fh * 33] *
              Om[(size_t)layer * 65536 + (size_t)fc * 257];
  }

  f32x4 accPV[2];
  accPV[0] = (f32x4){0.f, 0.f, 0.f, 0.f};
  accPV[1] = (f32x4){0.f, 0.f, 0.f, 0.f};
  float rsum[4] = {0.f, 0.f, 0.f, 0.f};

  const unsigned short* xk_base = xbf + ((size_t)b * S_) * D_ + h * DH_ + lg * 8;
  const unsigned short* vT_base = xnT + ((size_t)(b * D_ + h * DH_)) * S_;

  bf16x8 qkb[4];
#pragma unroll
  for (int c = 0; c < 4; c++)
    qkb[c] = *(const bf16x8*)(xk_base + (size_t)(c * 16 + lr) * D_);

  for (int kt = 0; kt < 16; kt++) {
    int k0 = kt * 64;
    bf16x8 pvb[2][2];
#pragma unroll
    for (int fs = 0; fs < 2; fs++)
#pragma unroll
      for (int kc = 0; kc < 2; kc++)
        pvb[fs][kc] = *(const bf16x8*)(vT_base + (size_t)(fs * 16 + lr) * S_ +
                                       k0 + kc * 32 + lg * 8);
    f32x4 s[4];
#pragma unroll
    for (int c = 0; c < 4; c++)
      s[c] = __builtin_amdgcn_mfma_f32_16x16x32_bf16(aq, qkb[c],
                (f32x4){0.f, 0.f, 0.f, 0.f}, 0, 0, 0);
    int ktn = kt < 15 ? kt + 1 : 15;
#pragma unroll
    for (int c = 0; c < 4; c++)
      qkb[c] = *(const bf16x8*)(xk_base + (size_t)(ktn * 64 + c * 16 + lr) * D_);
#pragma unroll
    for (int c = 0; c < 4; c++)
#pragma unroll
      for (int r = 0; r < 4; r++) {
        float p = __expf(s[c][r]);
        rsum[r] += p;
        P_lds[w][lg * 4 + r][c * 16 + lr] = f2bf(p);
      }
#pragma unroll
    for (int kc = 0; kc < 2; kc++) {
      bf16x8 pa = *(const bf16x8*)(&P_lds[w][lr][kc * 32 + lg * 8]);
#pragma unroll
      for (int fs = 0; fs < 2; fs++)
        accPV[fs] = __builtin_amdgcn_mfma_f32_16x16x32_bf16(pa, pvb[fs][kc],
                       accPV[fs], 0, 0, 0);
    }
  }

  float inv[4];
#pragma unroll
  for (int r = 0; r < 4; r++) {
    float v = rsum[r];
    v += __shfl_xor(v, 1, 64);
    v += __shfl_xor(v, 2, 64);
    v += __shfl_xor(v, 4, 64);
    v += __shfl_xor(v, 8, 64);
    inv[r] = 1.f / v;
  }
#pragma unroll
  for (int fs = 0; fs < 2; fs++)
#pragma unroll
    for (int r = 0; r < 4; r++) {
      float val = accPV[fs][r] * inv[r] * dvo[fs];
      y[((size_t)(b * S_ + q0 + lg * 4 + r)) * D_ + h * DH_ + fs * 16 + lr] = f2bf(val);
    }
}

// ---------------- fused MLP (3 GEMMs) + residual + next-layer LN ----------------
// A tiles [16][256] swizzled (BKB=512); W panel [256][64] swizzled (BKB=128).
__device__ __forceinline__ void mlp_mm(const unsigned short* A_lds,
                                       const unsigned short* __restrict__ W,
                                       unsigned short* Bp,
                                       f32x4 acc[2], int w, int lane, int lr16, int lg) {
  acc[0] = (f32x4){0.f, 0.f, 0.f, 0.f};
  acc[1] = (f32x4){0.f, 0.f, 0.f, 0.f};
  for (int k0 = 0; k0 < 256; k0 += 64) {
    __syncthreads();                              // Bp safe to overwrite
    stage_tile_swz<256, 64, 8>(W + k0, 256, Bp, w, lane);
    __syncthreads();                              // vmcnt drained -> Bp ready
#pragma unroll
    for (int kk = 0; kk < 64; kk += 32) {
      bf16x8 a = lds_frag<512>(A_lds, lr16, (k0 + kk) * 2 + lg * 16);
#pragma unroll
      for (int j = 0; j < 2; j++) {
        bf16x8 bfg = lds_frag<128>(Bp, w * 32 + j * 16 + lr16, kk * 2 + lg * 16);
        acc[j] = __builtin_amdgcn_mfma_f32_16x16x32_bf16(a, bfg, acc[j], 0, 0, 0);
      }
    }
  }
}

__device__ __forceinline__ void epi_gelu(const f32x4 acc[2], const float* __restrict__ bias,
                                         unsigned short* dst, int w, int lr16, int lg) {
#pragma unroll
  for (int j = 0; j < 2; j++) {
    int col = w * 32 + j * 16 + lr16;
    float bv = bias[col];
#pragma unroll
    for (int r = 0; r < 4; r++) {
      float v = acc[j][r] + bv;
      v = 0.5f * v * (1.f + erff(v * 0.70710678118654752f));
      int row = lg * 4 + r;
      int byte = (row * 512 + col * 2) ^ ((row & 7) << 4);
      *(unsigned short*)((char*)dst + byte) = f2bf(v);
    }
  }
}

template<int LAST>
__global__ __launch_bounds__(512) void k_mlp(
    const unsigned short* __restrict__ actA,  // attention out bf16 [4096][256]
    const unsigned short* __restrict__ Wl,    // 3 x [256 n][256 k] bf16 for this layer
    const float* __restrict__ b1, const float* __restrict__ b2, const float* __restrict__ b3,
    float* __restrict__ x,                    // residual f32 (in; out unless LAST)
    const float* __restrict__ lngN, const float* __restrict__ lnbN,  // next layer LN
    unsigned short* __restrict__ xbf, unsigned short* __restrict__ xnT,
    unsigned short* __restrict__ actB) {      // LAST: bf16 final x
  __shared__ __align__(16) unsigned short Aa[16 * 256];
  __shared__ __align__(16) unsigned short Ab[16 * 256];
  __shared__ __align__(16) unsigned short Ab2[16 * 256];
  __shared__ __align__(16) unsigned short Bp[256 * 64];
  __shared__ __align__(16) float xf[16][264];
  __shared__ float mrow[16], rrow[16];

  int r0 = blockIdx.x * 16;
  int tid = threadIdx.x;
  int w = tid >> 6, lane = tid & 63;
  int lr16 = lane & 15, lg = lane >> 4;

  stage_tile_swz<16, 256, 8>(actA + (size_t)r0 * D_, D_, Aa, w, lane);

  f32x4 acc[2];
  mlp_mm(Aa, Wl, Bp, acc, w, lane, lr16, lg);
  epi_gelu(acc, b1, Ab, w, lr16, lg);
  mlp_mm(Ab, Wl + 65536, Bp, acc, w, lane, lr16, lg);
  epi_gelu(acc, b2, Ab2, w, lr16, lg);
  mlp_mm(Ab2, Wl + 2 * 65536, Bp, acc, w, lane, lr16, lg);

  // epilogue: bias + residual
#pragma unroll
  for (int j = 0; j < 2; j++) {
    int col = w * 32 + j * 16 + lr16;
    float bv = b3[col];
#pragma unroll
    for (int r = 0; r < 4; r++) {
      int row = lg * 4 + r; int grow = r0 + row;
      float v = acc[j][r] + bv + x[(size_t)grow * D_ + col];
      if constexpr (LAST) {
        actB[(size_t)grow * D_ + col] = f2bf(v);
      } else {
        x[(size_t)grow * D_ + col] = v;
        xf[row][col] = v;
      }
    }
  }

  if constexpr (!LAST) {
    __syncthreads();
#pragma unroll
    for (int rr = 0; rr < 2; rr++) {
      int row = w * 2 + rr; int grow = r0 + row;
      f32x4 v = *(const f32x4*)&xf[row][lane * 4];
      float s = v[0] + v[1] + v[2] + v[3];
      float ss = v[0]*v[0] + v[1]*v[1] + v[2]*v[2] + v[3]*v[3];
#pragma unroll
      for (int off = 1; off < 64; off <<= 1) {
        s  += __shfl_xor(s, off, 64);
        ss += __shfl_xor(ss, off, 64);
      }
      float mean = s * (1.f / D_);
      float var = ss * (1.f / D_) - mean * mean;
      float rinv = rsqrtf(var + 1e-5f);
      float4 g4 = *(const float4*)(lngN + lane * 4);
      float4 b4 = *(const float4*)(lnbN + lane * 4);
      ushort4 o;
      o.x = f2bf((v[0] - mean) * rinv * g4.x + b4.x);
      o.y = f2bf((v[1] - mean) * rinv * g4.y + b4.y);
      o.z = f2bf((v[2] - mean) * rinv * g4.z + b4.z);
      o.w = f2bf((v[3] - mean) * rinv * g4.w + b4.w);
      *(ushort4*)(xbf + (size_t)grow * D_ + lane * 4) = o;
      if (lane == 0) { mrow[row] = mean; rrow[row] = rinv; }
    }
    __syncthreads();
    int d = tid & 255, half = tid >> 8;
    float gd = lngN[d], bd = lnbN[d];
    int bb = r0 >> 10, s0 = r0 & 1023;
    bf16x8 o8;
#pragma unroll
    for (int k = 0; k < 8; k++) {
      int srow = half * 8 + k;
      o8[k] = (short)f2bf((xf[srow][d] - mrow[srow]) * rrow[srow] * gd + bd);
    }
    *(bf16x8*)(xnT + ((size_t)(bb * 256 + d)) * S_ + s0 + half * 8) = o8;
  }
}

// ---------------- logits GEMM: single-stage full-K tiles, one barrier ----------------
// 8000 blocks (32 bm x 250 bn, bm fastest, XCD-swizzled) x 512 thr (8 waves 2x4).
// As/Bs = full-K 128x256 tiles (64 KB each), staged ONCE via global_load_lds,
// ONE vmcnt-drain+barrier, then 64 MFMA/thread with no further syncs.
__global__ __launch_bounds__(512) void k_logits(
    const unsigned short* __restrict__ A,    // bf16 [4096][256]
    const unsigned short* __restrict__ Bt,   // bf16 [32000][256]
    float* __restrict__ C) {                 // f32 [4096][32000]
  __shared__ __align__(16) unsigned short As[128 * 256];
  __shared__ __align__(16) unsigned short Bs[128 * 256];
  int tid = threadIdx.x, lane = tid & 63, w = tid >> 6;
  int wm = w >> 2, wn = w & 3;              // 2 (rows) x 4 (cols)
  int lr = lane & 15, lg = lane >> 4;

  int id = blockIdx.x;
  id = (id & 7) * 1000 + (id >> 3);         // bijective XCD swizzle (8000 % 8 == 0)
  int bm0 = (id & 31) * 128;                // bm fastest: 32 consecutive ids share B-panel
  int bn0 = (id >> 5) * 128;

  stage_tile_swz<128, 256, 8>(A + (size_t)bm0 * 256, 256, As, w, lane);
  stage_tile_swz<128, 256, 8>(Bt + (size_t)bn0 * 256, 256, Bs, w, lane);
  __syncthreads();                          // single vmcnt(0) drain

  f32x4 acc[4][2];
#pragma unroll
  for (int i = 0; i < 4; i++)
#pragma unroll
    for (int j = 0; j < 2; j++) acc[i][j] = (f32x4){0.f, 0.f, 0.f, 0.f};

#pragma unroll
  for (int ks = 0; ks < 8; ks++) {          // K = 8 x 32
    bf16x8 af[4], bfr[2];
#pragma unroll
    for (int i = 0; i < 4; i++)
      af[i] = lds_frag<512>(As, wm * 64 + i * 16 + lr, ks * 64 + lg * 16);
#pragma unroll
    for (int j = 0; j < 2; j++)
      bfr[j] = lds_frag<512>(Bs, wn * 32 + j * 16 + lr, ks * 64 + lg * 16);
#pragma unroll
    for (int i = 0; i < 4; i++)
#pragma unroll
      for (int j = 0; j < 2; j++)
        acc[i][j] = __builtin_amdgcn_mfma_f32_16x16x32_bf16(af[i], bfr[j], acc[i][j], 0, 0, 0);
  }

  int rbase = lg * 4;
#pragma unroll
  for (int i = 0; i < 4; i++)
#pragma unroll
    for (int j = 0; j < 2; j++) {
      int col = bn0 + wn * 32 + j * 16 + lr;
#pragma unroll
      for (int r = 0; r < 4; r++) {
        int row = bm0 + wm * 64 + i * 16 + rbase + r;
        C[(size_t)row * V_ + col] = acc[i][j][r];
      }
    }
}

// ---------------- transpose + f32->bf16 convert (weights) ----------------
__device__ __forceinline__ void tconv_tile(const float* __restrict__ in,
                                           unsigned short* __restrict__ out,
                                           int R, int C, int r0, int c0, int t) {
  __shared__ float tile[64][65];
#pragma unroll
  for (int i = 0; i < 16; i++) {
    int idx = i * 256 + t;
    int lr = idx >> 6, lc = idx & 63;
    tile[lr][lc] = in[(size_t)(r0 + lr) * C + c0 + lc];
  }
  __syncthreads();
#pragma unroll
  for (int i = 0; i < 16; i++) {
    int idx = i * 256 + t;
    int lr = idx >> 6, lc = idx & 63;
    out[(size_t)(c0 + lr) * R + r0 + lc] = f2bf(tile[lc][lr]);
  }
}

__global__ __launch_bounds__(256) void k_tconv(const float* __restrict__ in,
                                               unsigned short* __restrict__ out,
                                               int R, int C) {
  tconv_tile(in, out, R, C, blockIdx.y * 64, blockIdx.x * 64, threadIdx.x);
}

__global__ __launch_bounds__(256) void k_tconv_mlp(const float* __restrict__ w1,
                                                   const float* __restrict__ w2,
                                                   const float* __restrict__ w3,
                                                   unsigned short* __restrict__ out) {
  int z = blockIdx.z; int l = z / 3, mm = z % 3;
  const float* in = (mm == 0 ? w1 : mm == 1 ? w2 : w3) + (size_t)l * 65536;
  tconv_tile(in, out + (size_t)z * 65536, 256, 256, blockIdx.y * 64, blockIdx.x * 64, threadIdx.x);
}

// ---------------- launch ----------------
extern "C" void kernel_launch(void* const* d_in, const int* in_sizes, int n_in,
                              void* d_out, int out_size, void* d_ws, size_t ws_size,
                              hipStream_t stream) {
  const int*   X      = (const int*)d_in[0];
  const float* emb    = (const float*)d_in[1];
  const float* WQ     = (const float*)d_in[2];
  const float* WK     = (const float*)d_in[3];
  const float* WV     = (const float*)d_in[4];
  const float* Om     = (const float*)d_in[5];
  const float* lng    = (const float*)d_in[6];
  const float* lnb    = (const float*)d_in[7];
  const float* w1     = (const float*)d_in[8];
  const float* b1     = (const float*)d_in[9];
  const float* w2     = (const float*)d_in[10];
  const float* b2     = (const float*)d_in[11];
  const float* w3     = (const float*)d_in[12];
  const float* b3     = (const float*)d_in[13];
  const float* logitW = (const float*)d_in[14];
  float* out = (float*)d_out;
  char* ws = (char*)d_ws;

  constexpr size_t OFF_X    = 0;                      // f32 [4096][256]
  constexpr size_t OFF_XBF  = 4u * 1024 * 1024;       // bf16 [4096][256]
  constexpr size_t OFF_XNT  = 6u * 1024 * 1024;       // bf16 [4][256][1024]
  constexpr size_t OFF_ACTA = 8u * 1024 * 1024;       // bf16 [4096][256]
  constexpr size_t OFF_ACTB = 10u * 1024 * 1024;      // bf16 [4096][256]
  constexpr size_t OFF_MLPW = 12u * 1024 * 1024;      // bf16 12x[256][256] transposed
  constexpr size_t OFF_LWT  = OFF_MLPW + 12u * 65536 * 2; // bf16 [32000][256]

  float* x  = (float*)(ws + OFF_X);
  unsigned short* xbf  = (unsigned short*)(ws + OFF_XBF);
  unsigned short* xnT  = (unsigned short*)(ws + OFF_XNT);
  unsigned short* actA = (unsigned short*)(ws + OFF_ACTA);
  unsigned short* actB = (unsigned short*)(ws + OFF_ACTB);
  unsigned short* mlpW = (unsigned short*)(ws + OFF_MLPW);
  unsigned short* lWt  = (unsigned short*)(ws + OFF_LWT);

  // weight conversion (bf16, transposed to [N][K])
  k_tconv_mlp<<<dim3(4, 4, 12), 256, 0, stream>>>(w1, w2, w3, mlpW);
  k_tconv<<<dim3(500, 4), 256, 0, stream>>>(logitW, lWt, 256, 32000);

  k_embln<<<256, 512, 0, stream>>>(X, emb, lng, lnb, x, xbf, xnT);

  for (int l = 0; l < L_; l++) {
    k_attn2<<<B_ * (S_ / 16), 512, 0, stream>>>(xbf, xnT, WQ, WK, WV, Om, actA, l);
    if (l < L_ - 1) {
      k_mlp<0><<<256, 512, 0, stream>>>(actA, mlpW + (size_t)(l * 3) * 65536,
                                        b1 + (size_t)l * D_, b2 + (size_t)l * D_,
                                        b3 + (size_t)l * D_, x,
                                        lng + (size_t)(l + 1) * D_, lnb + (size_t)(l + 1) * D_,
                                        xbf, xnT, nullptr);
    } else {
      k_mlp<1><<<256, 512, 0, stream>>>(actA, mlpW + (size_t)(l * 3) * 65536,
                                        b1 + (size_t)l * D_, b2 + (size_t)l * D_,
                                        b3 + (size_t)l * D_, x,
                                        nullptr, nullptr, nullptr, nullptr, actB);
    }
  }

  // logits: 8000 blocks (32 bm x 250 bn), bm fastest, XCD-swizzled
  k_logits<<<8000, 512, 0, stream>>>(actB, lWt, out);
}

// Round 9
// 389.420 us; speedup vs baseline: 1.1194x; 1.1194x over previous
//
#include <hip/hip_runtime.h>
#include <hip/hip_bf16.h>
#include <cstdint>
#include <cstddef>

#define B_ 4
#define S_ 1024
#define V_ 32000
#define D_ 256
#define H_ 8
#define DH_ 32
#define L_ 4
#define MROWS (B_*S_)

typedef __attribute__((ext_vector_type(8))) short bf16x8;
typedef __attribute__((ext_vector_type(4))) float f32x4;

__device__ __forceinline__ unsigned short f2bf(float f) {
  union { float f; unsigned u; } c; c.f = f;
  unsigned u = c.u;
  u += 0x7fff + ((u >> 16) & 1);   // round-to-nearest-even
  return (unsigned short)(u >> 16);
}
__device__ __forceinline__ float bf2f(unsigned short u) {
  union { unsigned u; float f; } c; c.u = ((unsigned)u) << 16; return c.f;
}

// async global->LDS, 16B per lane; LDS dest is wave-uniform base + lane*16
__device__ __forceinline__ void gload16(const unsigned short* g, unsigned short* l) {
  __builtin_amdgcn_global_load_lds(
      (const __attribute__((address_space(1))) void*)g,
      (__attribute__((address_space(3))) void*)l, 16, 0, 0);
}

// ---- XOR-swizzled LDS tiles: lds[row][inner ^ ((row&7)<<4)] = g[row][inner]
template<int BM, int BK, int NW>
__device__ __forceinline__ void stage_tile_swz(const unsigned short* __restrict__ g, int ldg,
                                               unsigned short* lds, int wave, int lane) {
  constexpr int CH  = BM * BK * 2 / 1024;   // 1KB chunks
  constexpr int BKB = BK * 2;               // bytes per row
#pragma unroll
  for (int t = 0; t < CH / NW; ++t) {
    int c = wave + t * NW;
    int byte  = c * 1024 + lane * 16;
    int row   = byte / BKB;
    int inner = (byte % BKB) ^ ((row & 7) << 4);
    gload16(g + (size_t)row * ldg + (inner >> 1), lds + c * 512);
  }
}

// swizzled 16B fragment read: row-major [*][BKB/2] tile, kbytes multiple of 16
template<int BKB>
__device__ __forceinline__ bf16x8 lds_frag(const unsigned short* base, int row, int kbytes) {
  int b = (row * BKB + kbytes) ^ ((row & 7) << 4);
  return *(const bf16x8*)((const char*)base + b);
}

// ---------------- embed + LN(layer0) + dual-layout emit ----------------
__global__ __launch_bounds__(512) void k_embln(
    const int* __restrict__ X, const float* __restrict__ emb,
    const float* __restrict__ lng, const float* __restrict__ lnb,
    float* __restrict__ x, unsigned short* __restrict__ xbf,
    unsigned short* __restrict__ xnT) {
  __shared__ __align__(16) float xf[16][264];
  __shared__ float mrow[16], rrow[16];
  int r0 = blockIdx.x * 16;
  int tid = threadIdx.x;
  int w = tid >> 6, lane = tid & 63;
#pragma unroll
  for (int rr = 0; rr < 2; rr++) {
    int row = w * 2 + rr; int grow = r0 + row;
    int tok = X[grow];
    f32x4 v = *(const f32x4*)(emb + (size_t)tok * D_ + lane * 4);
    *(f32x4*)(x + (size_t)grow * D_ + lane * 4) = v;
    *(f32x4*)&xf[row][lane * 4] = v;
    float s = v[0] + v[1] + v[2] + v[3];
    float ss = v[0]*v[0] + v[1]*v[1] + v[2]*v[2] + v[3]*v[3];
#pragma unroll
    for (int off = 1; off < 64; off <<= 1) {
      s  += __shfl_xor(s, off, 64);
      ss += __shfl_xor(ss, off, 64);
    }
    float mean = s * (1.f / D_);
    float var = ss * (1.f / D_) - mean * mean;
    float rinv = rsqrtf(var + 1e-5f);
    float4 g4 = *(const float4*)(lng + lane * 4);
    float4 b4 = *(const float4*)(lnb + lane * 4);
    ushort4 o;
    o.x = f2bf((v[0] - mean) * rinv * g4.x + b4.x);
    o.y = f2bf((v[1] - mean) * rinv * g4.y + b4.y);
    o.z = f2bf((v[2] - mean) * rinv * g4.z + b4.z);
    o.w = f2bf((v[3] - mean) * rinv * g4.w + b4.w);
    *(ushort4*)(xbf + (size_t)grow * D_ + lane * 4) = o;
    if (lane == 0) { mrow[row] = mean; rrow[row] = rinv; }
  }
  __syncthreads();
  int d = tid & 255, half = tid >> 8;
  float gd = lng[d], bd = lnb[d];
  int bb = r0 >> 10, s0 = r0 & 1023;
  bf16x8 o8;
#pragma unroll
  for (int k = 0; k < 8; k++) {
    int srow = half * 8 + k;
    o8[k] = (short)f2bf((xf[srow][d] - mrow[srow]) * rrow[srow] * gd + bd);
  }
  *(bf16x8*)(xnT + ((size_t)(bb * 256 + d)) * S_ + s0 + half * 8) = o8;
}

// ---------------- MFMA attention ----------------
__global__ __launch_bounds__(512) void k_attn2(
    const unsigned short* __restrict__ xbf,   // [4096][256] bf16
    const unsigned short* __restrict__ xnT,   // [4][256][1024] bf16
    const float* __restrict__ WQ, const float* __restrict__ WK,
    const float* __restrict__ WV, const float* __restrict__ Om,
    unsigned short* __restrict__ y, int layer) {
  int b = blockIdx.x >> 6;
  int q0 = (blockIdx.x & 63) << 4;
  int tid = threadIdx.x;
  int w = tid >> 6, l = tid & 63;
  int lr = l & 15, lg = l >> 4;
  int h = w;

  __shared__ __align__(16) unsigned short P_lds[8][16][72];

  const float scale = 0.17677669529663687f;  // 1/sqrt(32)

  bf16x8 aq;
  {
    bf16x8 xq = *(const bf16x8*)(xbf + ((size_t)(b * S_ + q0 + lr)) * D_ + h * DH_ + lg * 8);
#pragma unroll
    for (int j = 0; j < 8; j++) {
      int dj = lg * 8 + j;
      float wq = WQ[((size_t)(layer * H_ + h)) * 1024 + dj * 33];
      float wk = WK[((size_t)(layer * H_ + h)) * 1024 + dj * 33];
      aq[j] = (short)f2bf(bf2f((unsigned short)xq[j]) * wq * wk * scale);
    }
  }
  float dvo[2];
#pragma unroll
  for (int fs = 0; fs < 2; fs++) {
    int fh = fs * 16 + lr;
    int fc = h * DH_ + fh;
    dvo[fs] = WV[((size_t)(layer * H_ + h)) * 1024 + fh * 33] *
              Om[(size_t)layer * 65536 + (size_t)fc * 257];
  }

  f32x4 accPV[2];
  accPV[0] = (f32x4){0.f, 0.f, 0.f, 0.f};
  accPV[1] = (f32x4){0.f, 0.f, 0.f, 0.f};
  float rsum[4] = {0.f, 0.f, 0.f, 0.f};

  const unsigned short* xk_base = xbf + ((size_t)b * S_) * D_ + h * DH_ + lg * 8;
  const unsigned short* vT_base = xnT + ((size_t)(b * D_ + h * DH_)) * S_;

  bf16x8 qkb[4];
#pragma unroll
  for (int c = 0; c < 4; c++)
    qkb[c] = *(const bf16x8*)(xk_base + (size_t)(c * 16 + lr) * D_);

  for (int kt = 0; kt < 16; kt++) {
    int k0 = kt * 64;
    bf16x8 pvb[2][2];
#pragma unroll
    for (int fs = 0; fs < 2; fs++)
#pragma unroll
      for (int kc = 0; kc < 2; kc++)
        pvb[fs][kc] = *(const bf16x8*)(vT_base + (size_t)(fs * 16 + lr) * S_ +
                                       k0 + kc * 32 + lg * 8);
    f32x4 s[4];
#pragma unroll
    for (int c = 0; c < 4; c++)
      s[c] = __builtin_amdgcn_mfma_f32_16x16x32_bf16(aq, qkb[c],
                (f32x4){0.f, 0.f, 0.f, 0.f}, 0, 0, 0);
    int ktn = kt < 15 ? kt + 1 : 15;
#pragma unroll
    for (int c = 0; c < 4; c++)
      qkb[c] = *(const bf16x8*)(xk_base + (size_t)(ktn * 64 + c * 16 + lr) * D_);
#pragma unroll
    for (int c = 0; c < 4; c++)
#pragma unroll
      for (int r = 0; r < 4; r++) {
        float p = __expf(s[c][r]);
        rsum[r] += p;
        P_lds[w][lg * 4 + r][c * 16 + lr] = f2bf(p);
      }
#pragma unroll
    for (int kc = 0; kc < 2; kc++) {
      bf16x8 pa = *(const bf16x8*)(&P_lds[w][lr][kc * 32 + lg * 8]);
#pragma unroll
      for (int fs = 0; fs < 2; fs++)
        accPV[fs] = __builtin_amdgcn_mfma_f32_16x16x32_bf16(pa, pvb[fs][kc],
                       accPV[fs], 0, 0, 0);
    }
  }

  float inv[4];
#pragma unroll
  for (int r = 0; r < 4; r++) {
    float v = rsum[r];
    v += __shfl_xor(v, 1, 64);
    v += __shfl_xor(v, 2, 64);
    v += __shfl_xor(v, 4, 64);
    v += __shfl_xor(v, 8, 64);
    inv[r] = 1.f / v;
  }
#pragma unroll
  for (int fs = 0; fs < 2; fs++)
#pragma unroll
    for (int r = 0; r < 4; r++) {
      float val = accPV[fs][r] * inv[r] * dvo[fs];
      y[((size_t)(b * S_ + q0 + lg * 4 + r)) * D_ + h * DH_ + fs * 16 + lr] = f2bf(val);
    }
}

// ---------------- fused MLP (3 GEMMs) + residual + next-layer LN ----------------
__device__ __forceinline__ void mlp_mm(const unsigned short* A_lds,
                                       const unsigned short* __restrict__ W,
                                       unsigned short* Bp,
                                       f32x4 acc[2], int w, int lane, int lr16, int lg) {
  acc[0] = (f32x4){0.f, 0.f, 0.f, 0.f};
  acc[1] = (f32x4){0.f, 0.f, 0.f, 0.f};
  for (int k0 = 0; k0 < 256; k0 += 64) {
    __syncthreads();                              // Bp safe to overwrite
    stage_tile_swz<256, 64, 8>(W + k0, 256, Bp, w, lane);
    __syncthreads();                              // vmcnt drained -> Bp ready
#pragma unroll
    for (int kk = 0; kk < 64; kk += 32) {
      bf16x8 a = lds_frag<512>(A_lds, lr16, (k0 + kk) * 2 + lg * 16);
#pragma unroll
      for (int j = 0; j < 2; j++) {
        bf16x8 bfg = lds_frag<128>(Bp, w * 32 + j * 16 + lr16, kk * 2 + lg * 16);
        acc[j] = __builtin_amdgcn_mfma_f32_16x16x32_bf16(a, bfg, acc[j], 0, 0, 0);
      }
    }
  }
}

__device__ __forceinline__ void epi_gelu(const f32x4 acc[2], const float* __restrict__ bias,
                                         unsigned short* dst, int w, int lr16, int lg) {
#pragma unroll
  for (int j = 0; j < 2; j++) {
    int col = w * 32 + j * 16 + lr16;
    float bv = bias[col];
#pragma unroll
    for (int r = 0; r < 4; r++) {
      float v = acc[j][r] + bv;
      v = 0.5f * v * (1.f + erff(v * 0.70710678118654752f));
      int row = lg * 4 + r;
      int byte = (row * 512 + col * 2) ^ ((row & 7) << 4);
      *(unsigned short*)((char*)dst + byte) = f2bf(v);
    }
  }
}

template<int LAST>
__global__ __launch_bounds__(512) void k_mlp(
    const unsigned short* __restrict__ actA,  // attention out bf16 [4096][256]
    const unsigned short* __restrict__ Wl,    // 3 x [256 n][256 k] bf16 for this layer
    const float* __restrict__ b1, const float* __restrict__ b2, const float* __restrict__ b3,
    float* __restrict__ x,                    // residual f32 (in; out unless LAST)
    const float* __restrict__ lngN, const float* __restrict__ lnbN,  // next layer LN
    unsigned short* __restrict__ xbf, unsigned short* __restrict__ xnT,
    unsigned short* __restrict__ actB) {      // LAST: bf16 final x
  __shared__ __align__(16) unsigned short Aa[16 * 256];
  __shared__ __align__(16) unsigned short Ab[16 * 256];
  __shared__ __align__(16) unsigned short Ab2[16 * 256];
  __shared__ __align__(16) unsigned short Bp[256 * 64];
  __shared__ __align__(16) float xf[16][264];
  __shared__ float mrow[16], rrow[16];

  int r0 = blockIdx.x * 16;
  int tid = threadIdx.x;
  int w = tid >> 6, lane = tid & 63;
  int lr16 = lane & 15, lg = lane >> 4;

  stage_tile_swz<16, 256, 8>(actA + (size_t)r0 * D_, D_, Aa, w, lane);

  f32x4 acc[2];
  mlp_mm(Aa, Wl, Bp, acc, w, lane, lr16, lg);
  epi_gelu(acc, b1, Ab, w, lr16, lg);
  mlp_mm(Ab, Wl + 65536, Bp, acc, w, lane, lr16, lg);
  epi_gelu(acc, b2, Ab2, w, lr16, lg);
  mlp_mm(Ab2, Wl + 2 * 65536, Bp, acc, w, lane, lr16, lg);

  // epilogue: bias + residual
#pragma unroll
  for (int j = 0; j < 2; j++) {
    int col = w * 32 + j * 16 + lr16;
    float bv = b3[col];
#pragma unroll
    for (int r = 0; r < 4; r++) {
      int row = lg * 4 + r; int grow = r0 + row;
      float v = acc[j][r] + bv + x[(size_t)grow * D_ + col];
      if constexpr (LAST) {
        actB[(size_t)grow * D_ + col] = f2bf(v);
      } else {
        x[(size_t)grow * D_ + col] = v;
        xf[row][col] = v;
      }
    }
  }

  if constexpr (!LAST) {
    __syncthreads();
#pragma unroll
    for (int rr = 0; rr < 2; rr++) {
      int row = w * 2 + rr; int grow = r0 + row;
      f32x4 v = *(const f32x4*)&xf[row][lane * 4];
      float s = v[0] + v[1] + v[2] + v[3];
      float ss = v[0]*v[0] + v[1]*v[1] + v[2]*v[2] + v[3]*v[3];
#pragma unroll
      for (int off = 1; off < 64; off <<= 1) {
        s  += __shfl_xor(s, off, 64);
        ss += __shfl_xor(ss, off, 64);
      }
      float mean = s * (1.f / D_);
      float var = ss * (1.f / D_) - mean * mean;
      float rinv = rsqrtf(var + 1e-5f);
      float4 g4 = *(const float4*)(lngN + lane * 4);
      float4 b4 = *(const float4*)(lnbN + lane * 4);
      ushort4 o;
      o.x = f2bf((v[0] - mean) * rinv * g4.x + b4.x);
      o.y = f2bf((v[1] - mean) * rinv * g4.y + b4.y);
      o.z = f2bf((v[2] - mean) * rinv * g4.z + b4.z);
      o.w = f2bf((v[3] - mean) * rinv * g4.w + b4.w);
      *(ushort4*)(xbf + (size_t)grow * D_ + lane * 4) = o;
      if (lane == 0) { mrow[row] = mean; rrow[row] = rinv; }
    }
    __syncthreads();
    int d = tid & 255, half = tid >> 8;
    float gd = lngN[d], bd = lnbN[d];
    int bb = r0 >> 10, s0 = r0 & 1023;
    bf16x8 o8;
#pragma unroll
    for (int k = 0; k < 8; k++) {
      int srow = half * 8 + k;
      o8[k] = (short)f2bf((xf[srow][d] - mrow[srow]) * rrow[srow] * gd + bd);
    }
    *(bf16x8*)(xnT + ((size_t)(bb * 256 + d)) * S_ + s0 + half * 8) = o8;
  }
}

// ---------------- bf16 MFMA GEMM (logits) ----------------
// SWZ==2: xcd owns bm-chunk; bn fastest within xcd -> concurrent blocks on an
// XCD write ADJACENT column-slabs of the SAME rows (streaming-like C writes).
template<int FM, int FN, int EPI, int SWZ>
__global__ __launch_bounds__(256) void k_gemm(
    const unsigned short* __restrict__ A,   // bf16 [M][256]
    const unsigned short* __restrict__ Bt,  // bf16 [N][256]
    const float* __restrict__ bias,
    void* __restrict__ Cout, int N, int nbm) {
  constexpr int BM = 32 * FM, BN = 32 * FN;
  constexpr int K = 256, BK = 64;
  __shared__ __align__(16) unsigned short As[BM * BK];
  __shared__ __align__(16) unsigned short Bs[BN * BK];

  int tid = threadIdx.x, lane = tid & 63, w = tid >> 6;
  int wm = w >> 1, wn = w & 1;

  int bm0, bn0;
  if constexpr (SWZ == 2) {
    int id = blockIdx.x;
    int xcd = id & 7;             // dispatch round-robin -> XCD
    int s = id >> 3;              // 0..999 within this XCD
    bn0 = (s % 250) * BN;         // bn FASTEST: write locality
    bm0 = (xcd * 4 + s / 250) * BM;
  } else {
    int id = blockIdx.x;
    bm0 = (id % nbm) * BM; bn0 = (id / nbm) * BN;
  }

  f32x4 acc[FM][FN];
#pragma unroll
  for (int i = 0; i < FM; i++)
#pragma unroll
    for (int j = 0; j < FN; j++) acc[i][j] = (f32x4){0.f, 0.f, 0.f, 0.f};

  int lr = lane & 15, lgb = (lane >> 4) * 16;   // k-offset bytes

  for (int k0 = 0; k0 < K; k0 += BK) {
    __syncthreads();
    stage_tile_swz<BM, BK, 4>(A + (size_t)bm0 * K + k0, K, As, w, lane);
    stage_tile_swz<BN, BK, 4>(Bt + (size_t)bn0 * K + k0, K, Bs, w, lane);
    __syncthreads();
#pragma unroll
    for (int kk = 0; kk < BK; kk += 32) {
      bf16x8 af[FM], bfr[FN];
#pragma unroll
      for (int i = 0; i < FM; i++)
        af[i] = lds_frag<128>(As, wm * FM * 16 + i * 16 + lr, kk * 2 + lgb);
#pragma unroll
      for (int j = 0; j < FN; j++)
        bfr[j] = lds_frag<128>(Bs, wn * FN * 16 + j * 16 + lr, kk * 2 + lgb);
#pragma unroll
      for (int i = 0; i < FM; i++)
#pragma unroll
        for (int j = 0; j < FN; j++)
          acc[i][j] = __builtin_amdgcn_mfma_f32_16x16x32_bf16(af[i], bfr[j], acc[i][j], 0, 0, 0);
    }
  }

  int rbase = (lane >> 4) * 4;
  int cl = lane & 15;
#pragma unroll
  for (int i = 0; i < FM; i++)
#pragma unroll
    for (int j = 0; j < FN; j++) {
      int col = bn0 + wn * FN * 16 + j * 16 + cl;
      float bv = 0.f;
      if constexpr (EPI != 0) bv = bias[col];
#pragma unroll
      for (int r = 0; r < 4; r++) {
        int row = bm0 + wm * FM * 16 + i * 16 + rbase + r;
        float v = acc[i][j][r] + bv;
        if constexpr (EPI == 0) {
          ((float*)Cout)[(size_t)row * N + col] = v;
        } else if constexpr (EPI == 1) {
          v = 0.5f * v * (1.f + erff(v * 0.70710678118654752f));
          ((unsigned short*)Cout)[(size_t)row * N + col] = f2bf(v);
        } else {
          ((float*)Cout)[(size_t)row * N + col] += v;
        }
      }
    }
}

// ---------------- transpose + f32->bf16 convert (weights) ----------------
__device__ __forceinline__ void tconv_tile(const float* __restrict__ in,
                                           unsigned short* __restrict__ out,
                                           int R, int C, int r0, int c0, int t) {
  __shared__ float tile[64][65];
#pragma unroll
  for (int i = 0; i < 16; i++) {
    int idx = i * 256 + t;
    int lr = idx >> 6, lc = idx & 63;
    tile[lr][lc] = in[(size_t)(r0 + lr) * C + c0 + lc];
  }
  __syncthreads();
#pragma unroll
  for (int i = 0; i < 16; i++) {
    int idx = i * 256 + t;
    int lr = idx >> 6, lc = idx & 63;
    out[(size_t)(c0 + lr) * R + r0 + lc] = f2bf(tile[lc][lr]);
  }
}

__global__ __launch_bounds__(256) void k_tconv(const float* __restrict__ in,
                                               unsigned short* __restrict__ out,
                                               int R, int C) {
  tconv_tile(in, out, R, C, blockIdx.y * 64, blockIdx.x * 64, threadIdx.x);
}

__global__ __launch_bounds__(256) void k_tconv_mlp(const float* __restrict__ w1,
                                                   const float* __restrict__ w2,
                                                   const float* __restrict__ w3,
                                                   unsigned short* __restrict__ out) {
  int z = blockIdx.z; int l = z / 3, mm = z % 3;
  const float* in = (mm == 0 ? w1 : mm == 1 ? w2 : w3) + (size_t)l * 65536;
  tconv_tile(in, out + (size_t)z * 65536, 256, 256, blockIdx.y * 64, blockIdx.x * 64, threadIdx.x);
}

// ---------------- launch ----------------
extern "C" void kernel_launch(void* const* d_in, const int* in_sizes, int n_in,
                              void* d_out, int out_size, void* d_ws, size_t ws_size,
                              hipStream_t stream) {
  const int*   X      = (const int*)d_in[0];
  const float* emb    = (const float*)d_in[1];
  const float* WQ     = (const float*)d_in[2];
  const float* WK     = (const float*)d_in[3];
  const float* WV     = (const float*)d_in[4];
  const float* Om     = (const float*)d_in[5];
  const float* lng    = (const float*)d_in[6];
  const float* lnb    = (const float*)d_in[7];
  const float* w1     = (const float*)d_in[8];
  const float* b1     = (const float*)d_in[9];
  const float* w2     = (const float*)d_in[10];
  const float* b2     = (const float*)d_in[11];
  const float* w3     = (const float*)d_in[12];
  const float* b3     = (const float*)d_in[13];
  const float* logitW = (const float*)d_in[14];
  float* out = (float*)d_out;
  char* ws = (char*)d_ws;

  constexpr size_t OFF_X    = 0;                      // f32 [4096][256]
  constexpr size_t OFF_XBF  = 4u * 1024 * 1024;       // bf16 [4096][256]
  constexpr size_t OFF_XNT  = 6u * 1024 * 1024;       // bf16 [4][256][1024]
  constexpr size_t OFF_ACTA = 8u * 1024 * 1024;       // bf16 [4096][256]
  constexpr size_t OFF_ACTB = 10u * 1024 * 1024;      // bf16 [4096][256]
  constexpr size_t OFF_MLPW = 12u * 1024 * 1024;      // bf16 12x[256][256] transposed
  constexpr size_t OFF_LWT  = OFF_MLPW + 12u * 65536 * 2; // bf16 [32000][256]

  float* x  = (float*)(ws + OFF_X);
  unsigned short* xbf  = (unsigned short*)(ws + OFF_XBF);
  unsigned short* xnT  = (unsigned short*)(ws + OFF_XNT);
  unsigned short* actA = (unsigned short*)(ws + OFF_ACTA);
  unsigned short* actB = (unsigned short*)(ws + OFF_ACTB);
  unsigned short* mlpW = (unsigned short*)(ws + OFF_MLPW);
  unsigned short* lWt  = (unsigned short*)(ws + OFF_LWT);

  // weight conversion (bf16, transposed to [N][K])
  k_tconv_mlp<<<dim3(4, 4, 12), 256, 0, stream>>>(w1, w2, w3, mlpW);
  k_tconv<<<dim3(500, 4), 256, 0, stream>>>(logitW, lWt, 256, 32000);

  k_embln<<<256, 512, 0, stream>>>(X, emb, lng, lnb, x, xbf, xnT);

  for (int l = 0; l < L_; l++) {
    k_attn2<<<B_ * (S_ / 16), 512, 0, stream>>>(xbf, xnT, WQ, WK, WV, Om, actA, l);
    if (l < L_ - 1) {
      k_mlp<0><<<256, 512, 0, stream>>>(actA, mlpW + (size_t)(l * 3) * 65536,
                                        b1 + (size_t)l * D_, b2 + (size_t)l * D_,
                                        b3 + (size_t)l * D_, x,
                                        lng + (size_t)(l + 1) * D_, lnb + (size_t)(l + 1) * D_,
                                        xbf, xnT, nullptr);
    } else {
      k_mlp<1><<<256, 512, 0, stream>>>(actA, mlpW + (size_t)(l * 3) * 65536,
                                        b1 + (size_t)l * D_, b2 + (size_t)l * D_,
                                        b3 + (size_t)l * D_, x,
                                        nullptr, nullptr, nullptr, nullptr, actB);
    }
  }

  // logits: 8000 blocks; xcd-chunked bm, bn-fastest (write locality)
  k_gemm<4, 4, 0, 2><<<8000, 256, 0, stream>>>(actB, lWt, nullptr, out, 32000, 32);
}

// Round 10
// 364.060 us; speedup vs baseline: 1.1974x; 1.0697x over previous
//
#include <hip/hip_runtime.h>
#include <hip/hip_bf16.h>
#include <cstdint>
#include <cstddef>

#define B_ 4
#define S_ 1024
#define V_ 32000
#define D_ 256
#define H_ 8
#define DH_ 32
#define L_ 4
#define MROWS (B_*S_)

typedef __attribute__((ext_vector_type(8))) short bf16x8;
typedef __attribute__((ext_vector_type(4))) float f32x4;

__device__ __forceinline__ unsigned short f2bf(float f) {
  union { float f; unsigned u; } c; c.f = f;
  unsigned u = c.u;
  u += 0x7fff + ((u >> 16) & 1);   // round-to-nearest-even
  return (unsigned short)(u >> 16);
}
__device__ __forceinline__ float bf2f(unsigned short u) {
  union { unsigned u; float f; } c; c.u = ((unsigned)u) << 16; return c.f;
}

// async global->LDS, 16B per lane; LDS dest is wave-uniform base + lane*16
__device__ __forceinline__ void gload16(const unsigned short* g, unsigned short* l) {
  __builtin_amdgcn_global_load_lds(
      (const __attribute__((address_space(1))) void*)g,
      (__attribute__((address_space(3))) void*)l, 16, 0, 0);
}

// ---- XOR-swizzled LDS tiles: lds[row][inner ^ ((row&7)<<4)] = g[row][inner]
template<int BM, int BK, int NW>
__device__ __forceinline__ void stage_tile_swz(const unsigned short* __restrict__ g, int ldg,
                                               unsigned short* lds, int wave, int lane) {
  constexpr int CH  = BM * BK * 2 / 1024;   // 1KB chunks
  constexpr int BKB = BK * 2;               // bytes per row
#pragma unroll
  for (int t = 0; t < CH / NW; ++t) {
    int c = wave + t * NW;
    int byte  = c * 1024 + lane * 16;
    int row   = byte / BKB;
    int inner = (byte % BKB) ^ ((row & 7) << 4);
    gload16(g + (size_t)row * ldg + (inner >> 1), lds + c * 512);
  }
}

// swizzled 16B fragment read: row-major [*][BKB/2] tile, kbytes multiple of 16
template<int BKB>
__device__ __forceinline__ bf16x8 lds_frag(const unsigned short* base, int row, int kbytes) {
  int b = (row * BKB + kbytes) ^ ((row & 7) << 4);
  return *(const bf16x8*)((const char*)base + b);
}

// ---------------- embed + LN(layer0) + dual-layout emit ----------------
__global__ __launch_bounds__(512) void k_embln(
    const int* __restrict__ X, const float* __restrict__ emb,
    const float* __restrict__ lng, const float* __restrict__ lnb,
    float* __restrict__ x, unsigned short* __restrict__ xbf,
    unsigned short* __restrict__ xnT) {
  __shared__ __align__(16) float xf[16][264];
  __shared__ float mrow[16], rrow[16];
  int r0 = blockIdx.x * 16;
  int tid = threadIdx.x;
  int w = tid >> 6, lane = tid & 63;
#pragma unroll
  for (int rr = 0; rr < 2; rr++) {
    int row = w * 2 + rr; int grow = r0 + row;
    int tok = X[grow];
    f32x4 v = *(const f32x4*)(emb + (size_t)tok * D_ + lane * 4);
    *(f32x4*)(x + (size_t)grow * D_ + lane * 4) = v;
    *(f32x4*)&xf[row][lane * 4] = v;
    float s = v[0] + v[1] + v[2] + v[3];
    float ss = v[0]*v[0] + v[1]*v[1] + v[2]*v[2] + v[3]*v[3];
#pragma unroll
    for (int off = 1; off < 64; off <<= 1) {
      s  += __shfl_xor(s, off, 64);
      ss += __shfl_xor(ss, off, 64);
    }
    float mean = s * (1.f / D_);
    float var = ss * (1.f / D_) - mean * mean;
    float rinv = rsqrtf(var + 1e-5f);
    float4 g4 = *(const float4*)(lng + lane * 4);
    float4 b4 = *(const float4*)(lnb + lane * 4);
    ushort4 o;
    o.x = f2bf((v[0] - mean) * rinv * g4.x + b4.x);
    o.y = f2bf((v[1] - mean) * rinv * g4.y + b4.y);
    o.z = f2bf((v[2] - mean) * rinv * g4.z + b4.z);
    o.w = f2bf((v[3] - mean) * rinv * g4.w + b4.w);
    *(ushort4*)(xbf + (size_t)grow * D_ + lane * 4) = o;
    if (lane == 0) { mrow[row] = mean; rrow[row] = rinv; }
  }
  __syncthreads();
  int d = tid & 255, half = tid >> 8;
  float gd = lng[d], bd = lnb[d];
  int bb = r0 >> 10, s0 = r0 & 1023;
  bf16x8 o8;
#pragma unroll
  for (int k = 0; k < 8; k++) {
    int srow = half * 8 + k;
    o8[k] = (short)f2bf((xf[srow][d] - mrow[srow]) * rrow[srow] * gd + bd);
  }
  *(bf16x8*)(xnT + ((size_t)(bb * 256 + d)) * S_ + s0 + half * 8) = o8;
}

// ---------------- fused layer: MFMA attention + 3-GEMM MLP + residual + next LN ----
// 256 blocks (b,q0) x 512 thr (8 waves). Attn: wave w = head w, 16 q-rows; output
// written straight to LDS Aa (swizzled) -- actA never hits global. MLP: 12 W panels
// streamed through 2-buffer Bp with next-panel prefetch issued BEFORE compute
// (T3-minimum), plain __syncthreads per panel. xbf/xnT are double-buffered across
// layers (fusion makes in-place overwrite a cross-block race).
template<int LAST>
__global__ __launch_bounds__(512) void k_layer(
    const unsigned short* __restrict__ xbf,   // layer input  [4096][256] bf16
    const unsigned short* __restrict__ xnT,   // layer input  [4][256][1024] bf16
    const float* __restrict__ WQ, const float* __restrict__ WK,
    const float* __restrict__ WV, const float* __restrict__ Om,
    const unsigned short* __restrict__ Wl,    // 3 x [256][256] bf16 (this layer)
    const float* __restrict__ b1, const float* __restrict__ b2, const float* __restrict__ b3,
    float* __restrict__ x,                    // residual f32
    const float* __restrict__ lngN, const float* __restrict__ lnbN,
    unsigned short* __restrict__ xbfN, unsigned short* __restrict__ xnTN,  // outputs (!LAST)
    unsigned short* __restrict__ actB,        // output (LAST)
    int layer) {
  __shared__ __align__(16) unsigned short P_lds[8][16][72];
  __shared__ __align__(16) unsigned short Aa[16 * 256];
  __shared__ __align__(16) unsigned short Ab[16 * 256];
  __shared__ __align__(16) unsigned short Ab2[16 * 256];
  __shared__ __align__(16) unsigned short Bp[2][256 * 64];
  __shared__ __align__(16) float xf[16][264];
  __shared__ float mrow[16], rrow[16];

  int b = blockIdx.x >> 6;
  int q0 = (blockIdx.x & 63) << 4;
  int r0 = blockIdx.x * 16;                  // == b*S + q0
  int tid = threadIdx.x;
  int w = tid >> 6, lane = tid & 63;
  int lr = lane & 15, lg = lane >> 4;
  int h = w;

  // prefetch MLP W panel 0 (drained at the post-attention barrier)
  stage_tile_swz<256, 64, 8>(Wl, 256, Bp[0], w, lane);

  // ================= attention =================
  const float scale = 0.17677669529663687f;  // 1/sqrt(32)
  bf16x8 aq;
  {
    bf16x8 xq = *(const bf16x8*)(xbf + ((size_t)(b * S_ + q0 + lr)) * D_ + h * DH_ + lg * 8);
#pragma unroll
    for (int j = 0; j < 8; j++) {
      int dj = lg * 8 + j;
      float wq = WQ[((size_t)(layer * H_ + h)) * 1024 + dj * 33];
      float wk = WK[((size_t)(layer * H_ + h)) * 1024 + dj * 33];
      aq[j] = (short)f2bf(bf2f((unsigned short)xq[j]) * wq * wk * scale);
    }
  }
  float dvo[2];
#pragma unroll
  for (int fs = 0; fs < 2; fs++) {
    int fh = fs * 16 + lr;
    int fc = h * DH_ + fh;
    dvo[fs] = WV[((size_t)(layer * H_ + h)) * 1024 + fh * 33] *
              Om[(size_t)layer * 65536 + (size_t)fc * 257];
  }

  f32x4 accPV[2];
  accPV[0] = (f32x4){0.f, 0.f, 0.f, 0.f};
  accPV[1] = (f32x4){0.f, 0.f, 0.f, 0.f};
  float rsum[4] = {0.f, 0.f, 0.f, 0.f};

  const unsigned short* xk_base = xbf + ((size_t)b * S_) * D_ + h * DH_ + lg * 8;
  const unsigned short* vT_base = xnT + ((size_t)(b * D_ + h * DH_)) * S_;

  bf16x8 qkb[4];
#pragma unroll
  for (int c = 0; c < 4; c++)
    qkb[c] = *(const bf16x8*)(xk_base + (size_t)(c * 16 + lr) * D_);

  for (int kt = 0; kt < 16; kt++) {
    int k0 = kt * 64;
    bf16x8 pvb[2][2];
#pragma unroll
    for (int fs = 0; fs < 2; fs++)
#pragma unroll
      for (int kc = 0; kc < 2; kc++)
        pvb[fs][kc] = *(const bf16x8*)(vT_base + (size_t)(fs * 16 + lr) * S_ +
                                       k0 + kc * 32 + lg * 8);
    f32x4 s[4];
#pragma unroll
    for (int c = 0; c < 4; c++)
      s[c] = __builtin_amdgcn_mfma_f32_16x16x32_bf16(aq, qkb[c],
                (f32x4){0.f, 0.f, 0.f, 0.f}, 0, 0, 0);
    int ktn = kt < 15 ? kt + 1 : 15;
#pragma unroll
    for (int c = 0; c < 4; c++)
      qkb[c] = *(const bf16x8*)(xk_base + (size_t)(ktn * 64 + c * 16 + lr) * D_);
#pragma unroll
    for (int c = 0; c < 4; c++)
#pragma unroll
      for (int r = 0; r < 4; r++) {
        float p = __expf(s[c][r]);
        rsum[r] += p;
        P_lds[w][lg * 4 + r][c * 16 + lr] = f2bf(p);
      }
#pragma unroll
    for (int kc = 0; kc < 2; kc++) {
      bf16x8 pa = *(const bf16x8*)(&P_lds[w][lr][kc * 32 + lg * 8]);
#pragma unroll
      for (int fs = 0; fs < 2; fs++)
        accPV[fs] = __builtin_amdgcn_mfma_f32_16x16x32_bf16(pa, pvb[fs][kc],
                       accPV[fs], 0, 0, 0);
    }
  }

  float inv[4];
#pragma unroll
  for (int r = 0; r < 4; r++) {
    float v = rsum[r];
    v += __shfl_xor(v, 1, 64);
    v += __shfl_xor(v, 2, 64);
    v += __shfl_xor(v, 4, 64);
    v += __shfl_xor(v, 8, 64);
    inv[r] = 1.f / v;
  }
  // attention out -> LDS Aa (swizzled [16][256], BKB=512)
#pragma unroll
  for (int fs = 0; fs < 2; fs++)
#pragma unroll
    for (int r = 0; r < 4; r++) {
      float val = accPV[fs][r] * inv[r] * dvo[fs];
      int row = lg * 4 + r, col = h * DH_ + fs * 16 + lr;
      int byte = (row * 512 + col * 2) ^ ((row & 7) << 4);
      *(unsigned short*)((char*)Aa + byte) = f2bf(val);
    }
  __syncthreads();   // Aa visible to all waves; W panel 0 drained

  // ================= MLP: 12 panels (3 gemms x 4 k-steps), prefetch pipeline ====
  int lr16 = lr;
  f32x4 acc[2];
  acc[0] = (f32x4){0.f, 0.f, 0.f, 0.f};
  acc[1] = (f32x4){0.f, 0.f, 0.f, 0.f};
  const unsigned short* Asrc = Aa;

  for (int p = 0; p < 12; ++p) {
    if (p < 11) {
      int pn = p + 1;
      stage_tile_swz<256, 64, 8>(Wl + (size_t)(pn >> 2) * 65536 + (pn & 3) * 64,
                                 256, Bp[pn & 1], w, lane);
    }
    int kk0 = (p & 3) * 64;
#pragma unroll
    for (int kk = 0; kk < 64; kk += 32) {
      bf16x8 a = lds_frag<512>(Asrc, lr16, (kk0 + kk) * 2 + lg * 16);
#pragma unroll
      for (int j = 0; j < 2; j++) {
        bf16x8 bfg = lds_frag<128>(Bp[p & 1], w * 32 + j * 16 + lr16, kk * 2 + lg * 16);
        acc[j] = __builtin_amdgcn_mfma_f32_16x16x32_bf16(a, bfg, acc[j], 0, 0, 0);
      }
    }
    if (p == 3 || p == 7) {
      const float* bias = (p == 3) ? b1 : b2;
      unsigned short* dst = (p == 3) ? Ab : Ab2;
#pragma unroll
      for (int j = 0; j < 2; j++) {
        int col = w * 32 + j * 16 + lr16;
        float bv = bias[col];
#pragma unroll
        for (int r = 0; r < 4; r++) {
          float v = acc[j][r] + bv;
          v = 0.5f * v * (1.f + erff(v * 0.70710678118654752f));
          int row = lg * 4 + r;
          int byte = (row * 512 + col * 2) ^ ((row & 7) << 4);
          *(unsigned short*)((char*)dst + byte) = f2bf(v);
        }
      }
      acc[0] = (f32x4){0.f, 0.f, 0.f, 0.f};
      acc[1] = (f32x4){0.f, 0.f, 0.f, 0.f};
      Asrc = (p == 3) ? Ab : Ab2;
    }
    __syncthreads();
  }

  // ---- final epilogue: bias3 + residual (+ next-layer LN dual emit) ----
#pragma unroll
  for (int j = 0; j < 2; j++) {
    int col = w * 32 + j * 16 + lr16;
    float bv = b3[col];
#pragma unroll
    for (int r = 0; r < 4; r++) {
      int row = lg * 4 + r; int grow = r0 + row;
      float v = acc[j][r] + bv + x[(size_t)grow * D_ + col];
      if constexpr (LAST) {
        actB[(size_t)grow * D_ + col] = f2bf(v);
      } else {
        x[(size_t)grow * D_ + col] = v;
        xf[row][col] = v;
      }
    }
  }

  if constexpr (!LAST) {
    __syncthreads();
#pragma unroll
    for (int rr = 0; rr < 2; rr++) {
      int row = w * 2 + rr; int grow = r0 + row;
      f32x4 v = *(const f32x4*)&xf[row][lane * 4];
      float s = v[0] + v[1] + v[2] + v[3];
      float ss = v[0]*v[0] + v[1]*v[1] + v[2]*v[2] + v[3]*v[3];
#pragma unroll
      for (int off = 1; off < 64; off <<= 1) {
        s  += __shfl_xor(s, off, 64);
        ss += __shfl_xor(ss, off, 64);
      }
      float mean = s * (1.f / D_);
      float var = ss * (1.f / D_) - mean * mean;
      float rinv = rsqrtf(var + 1e-5f);
      float4 g4 = *(const float4*)(lngN + lane * 4);
      float4 b4 = *(const float4*)(lnbN + lane * 4);
      ushort4 o;
      o.x = f2bf((v[0] - mean) * rinv * g4.x + b4.x);
      o.y = f2bf((v[1] - mean) * rinv * g4.y + b4.y);
      o.z = f2bf((v[2] - mean) * rinv * g4.z + b4.z);
      o.w = f2bf((v[3] - mean) * rinv * g4.w + b4.w);
      *(ushort4*)(xbfN + (size_t)grow * D_ + lane * 4) = o;
      if (lane == 0) { mrow[row] = mean; rrow[row] = rinv; }
    }
    __syncthreads();
    int d = tid & 255, half = tid >> 8;
    float gd = lngN[d], bd = lnbN[d];
    int bb = r0 >> 10, s0 = r0 & 1023;
    bf16x8 o8;
#pragma unroll
    for (int k = 0; k < 8; k++) {
      int srow = half * 8 + k;
      o8[k] = (short)f2bf((xf[srow][d] - mrow[srow]) * rrow[srow] * gd + bd);
    }
    *(bf16x8*)(xnTN + ((size_t)(bb * 256 + d)) * S_ + s0 + half * 8) = o8;
  }
}

// ---------------- logits GEMM: 128x128 tile, double-buffered K with prefetch ------
// T3-minimum: issue K-step t+1's global_load_lds BEFORE computing step t; one
// __syncthreads per step (its vmcnt(0) drain lands after compute hides latency).
__global__ __launch_bounds__(256) void k_logits(
    const unsigned short* __restrict__ A,    // bf16 [4096][256]
    const unsigned short* __restrict__ Bt,   // bf16 [32000][256]
    float* __restrict__ C) {
  __shared__ __align__(16) unsigned short As[2][128 * 64];
  __shared__ __align__(16) unsigned short Bs[2][128 * 64];

  int tid = threadIdx.x, lane = tid & 63, w = tid >> 6;
  int wm = w >> 1, wn = w & 1;

  int id = blockIdx.x;
  int xcd = id & 7;
  int s = id >> 3;
  int bn0 = (s % 250) * 128;
  int bm0 = (xcd * 4 + s / 250) * 128;

  f32x4 acc[4][4];
#pragma unroll
  for (int i = 0; i < 4; i++)
#pragma unroll
    for (int j = 0; j < 4; j++) acc[i][j] = (f32x4){0.f, 0.f, 0.f, 0.f};

  int lr = lane & 15, lgb = (lane >> 4) * 16;

  stage_tile_swz<128, 64, 4>(A + (size_t)bm0 * 256, 256, As[0], w, lane);
  stage_tile_swz<128, 64, 4>(Bt + (size_t)bn0 * 256, 256, Bs[0], w, lane);
  __syncthreads();

  for (int t = 0; t < 4; ++t) {
    int cur = t & 1;
    if (t < 3) {
      stage_tile_swz<128, 64, 4>(A + (size_t)bm0 * 256 + (t + 1) * 64, 256, As[cur ^ 1], w, lane);
      stage_tile_swz<128, 64, 4>(Bt + (size_t)bn0 * 256 + (t + 1) * 64, 256, Bs[cur ^ 1], w, lane);
    }
#pragma unroll
    for (int kk = 0; kk < 64; kk += 32) {
      bf16x8 af[4], bfr[4];
#pragma unroll
      for (int i = 0; i < 4; i++)
        af[i] = lds_frag<128>(As[cur], wm * 64 + i * 16 + lr, kk * 2 + lgb);
#pragma unroll
      for (int j = 0; j < 4; j++)
        bfr[j] = lds_frag<128>(Bs[cur], wn * 64 + j * 16 + lr, kk * 2 + lgb);
#pragma unroll
      for (int i = 0; i < 4; i++)
#pragma unroll
        for (int j = 0; j < 4; j++)
          acc[i][j] = __builtin_amdgcn_mfma_f32_16x16x32_bf16(af[i], bfr[j], acc[i][j], 0, 0, 0);
    }
    __syncthreads();
  }

  int rbase = (lane >> 4) * 4;
  int cl = lane & 15;
#pragma unroll
  for (int i = 0; i < 4; i++)
#pragma unroll
    for (int j = 0; j < 4; j++) {
      int col = bn0 + wn * 64 + j * 16 + cl;
#pragma unroll
      for (int r = 0; r < 4; r++) {
        int row = bm0 + wm * 64 + i * 16 + rbase + r;
        C[(size_t)row * V_ + col] = acc[i][j][r];
      }
    }
}

// ---------------- transpose + f32->bf16 convert (weights) ----------------
__device__ __forceinline__ void tconv_tile(const float* __restrict__ in,
                                           unsigned short* __restrict__ out,
                                           int R, int C, int r0, int c0, int t) {
  __shared__ float tile[64][65];
#pragma unroll
  for (int i = 0; i < 16; i++) {
    int idx = i * 256 + t;
    int lr = idx >> 6, lc = idx & 63;
    tile[lr][lc] = in[(size_t)(r0 + lr) * C + c0 + lc];
  }
  __syncthreads();
#pragma unroll
  for (int i = 0; i < 16; i++) {
    int idx = i * 256 + t;
    int lr = idx >> 6, lc = idx & 63;
    out[(size_t)(c0 + lr) * R + r0 + lc] = f2bf(tile[lc][lr]);
  }
}

__global__ __launch_bounds__(256) void k_tconv(const float* __restrict__ in,
                                               unsigned short* __restrict__ out,
                                               int R, int C) {
  tconv_tile(in, out, R, C, blockIdx.y * 64, blockIdx.x * 64, threadIdx.x);
}

__global__ __launch_bounds__(256) void k_tconv_mlp(const float* __restrict__ w1,
                                                   const float* __restrict__ w2,
                                                   const float* __restrict__ w3,
                                                   unsigned short* __restrict__ out) {
  int z = blockIdx.z; int l = z / 3, mm = z % 3;
  const float* in = (mm == 0 ? w1 : mm == 1 ? w2 : w3) + (size_t)l * 65536;
  tconv_tile(in, out + (size_t)z * 65536, 256, 256, blockIdx.y * 64, blockIdx.x * 64, threadIdx.x);
}

// ---------------- launch ----------------
extern "C" void kernel_launch(void* const* d_in, const int* in_sizes, int n_in,
                              void* d_out, int out_size, void* d_ws, size_t ws_size,
                              hipStream_t stream) {
  const int*   X      = (const int*)d_in[0];
  const float* emb    = (const float*)d_in[1];
  const float* WQ     = (const float*)d_in[2];
  const float* WK     = (const float*)d_in[3];
  const float* WV     = (const float*)d_in[4];
  const float* Om     = (const float*)d_in[5];
  const float* lng    = (const float*)d_in[6];
  const float* lnb    = (const float*)d_in[7];
  const float* w1     = (const float*)d_in[8];
  const float* b1     = (const float*)d_in[9];
  const float* w2     = (const float*)d_in[10];
  const float* b2     = (const float*)d_in[11];
  const float* w3     = (const float*)d_in[12];
  const float* b3     = (const float*)d_in[13];
  const float* logitW = (const float*)d_in[14];
  float* out = (float*)d_out;
  char* ws = (char*)d_ws;

  constexpr size_t MB = 1024u * 1024;
  float* x  = (float*)(ws);                                    // 4 MB
  unsigned short* xbf0 = (unsigned short*)(ws + 4 * MB);       // 2 MB
  unsigned short* xbf1 = (unsigned short*)(ws + 6 * MB);       // 2 MB
  unsigned short* xnT0 = (unsigned short*)(ws + 8 * MB);       // 2 MB
  unsigned short* xnT1 = (unsigned short*)(ws + 10 * MB);      // 2 MB
  unsigned short* actB = (unsigned short*)(ws + 12 * MB);      // 2 MB
  unsigned short* mlpW = (unsigned short*)(ws + 14 * MB);      // 1.5 MB
  unsigned short* lWt  = (unsigned short*)(ws + 16 * MB);      // 16 MB

  // weight conversion (bf16, transposed to [N][K])
  k_tconv_mlp<<<dim3(4, 4, 12), 256, 0, stream>>>(w1, w2, w3, mlpW);
  k_tconv<<<dim3(500, 4), 256, 0, stream>>>(logitW, lWt, 256, 32000);

  k_embln<<<256, 512, 0, stream>>>(X, emb, lng, lnb, x, xbf0, xnT0);

  for (int l = 0; l < L_; l++) {
    const unsigned short* xbfI = (l & 1) ? xbf1 : xbf0;
    const unsigned short* xnTI = (l & 1) ? xnT1 : xnT0;
    unsigned short* xbfO = (l & 1) ? xbf0 : xbf1;
    unsigned short* xnTO = (l & 1) ? xnT0 : xnT1;
    if (l < L_ - 1) {
      k_layer<0><<<256, 512, 0, stream>>>(
          xbfI, xnTI, WQ, WK, WV, Om, mlpW + (size_t)(l * 3) * 65536,
          b1 + (size_t)l * D_, b2 + (size_t)l * D_, b3 + (size_t)l * D_, x,
          lng + (size_t)(l + 1) * D_, lnb + (size_t)(l + 1) * D_,
          xbfO, xnTO, nullptr, l);
    } else {
      k_layer<1><<<256, 512, 0, stream>>>(
          xbfI, xnTI, WQ, WK, WV, Om, mlpW + (size_t)(l * 3) * 65536,
          b1 + (size_t)l * D_, b2 + (size_t)l * D_, b3 + (size_t)l * D_, x,
          nullptr, nullptr, nullptr, nullptr, actB, l);
    }
  }

  // logits: 8000 blocks; xcd-chunked bm, bn-fastest, K-step double-buffer prefetch
  k_logits<<<8000, 256, 0, stream>>>(actB, lWt, out);
}

// Round 11
// 355.454 us; speedup vs baseline: 1.2264x; 1.0242x over previous
//
#include <hip/hip_runtime.h>
#include <hip/hip_bf16.h>
#include <cstdint>
#include <cstddef>

#define B_ 4
#define S_ 1024
#define V_ 32000
#define D_ 256
#define H_ 8
#define DH_ 32
#define L_ 4
#define MROWS (B_*S_)

typedef __attribute__((ext_vector_type(8))) short bf16x8;
typedef __attribute__((ext_vector_type(4))) float f32x4;

__device__ __forceinline__ unsigned short f2bf(float f) {
  union { float f; unsigned u; } c; c.f = f;
  unsigned u = c.u;
  u += 0x7fff + ((u >> 16) & 1);   // round-to-nearest-even
  return (unsigned short)(u >> 16);
}
__device__ __forceinline__ float bf2f(unsigned short u) {
  union { unsigned u; float f; } c; c.u = ((unsigned)u) << 16; return c.f;
}

// async global->LDS, 16B per lane; LDS dest is wave-uniform base + lane*16
__device__ __forceinline__ void gload16(const unsigned short* g, unsigned short* l) {
  __builtin_amdgcn_global_load_lds(
      (const __attribute__((address_space(1))) void*)g,
      (__attribute__((address_space(3))) void*)l, 16, 0, 0);
}

// ---- XOR-swizzled LDS tiles: lds[row][inner ^ ((row&7)<<4)] = g[row][inner]
template<int BM, int BK, int NW>
__device__ __forceinline__ void stage_tile_swz(const unsigned short* __restrict__ g, int ldg,
                                               unsigned short* lds, int wave, int lane) {
  constexpr int CH  = BM * BK * 2 / 1024;   // 1KB chunks
  constexpr int BKB = BK * 2;               // bytes per row
#pragma unroll
  for (int t = 0; t < CH / NW; ++t) {
    int c = wave + t * NW;
    int byte  = c * 1024 + lane * 16;
    int row   = byte / BKB;
    int inner = (byte % BKB) ^ ((row & 7) << 4);
    gload16(g + (size_t)row * ldg + (inner >> 1), lds + c * 512);
  }
}

// swizzled 16B fragment read: row-major [*][BKB/2] tile, kbytes multiple of 16
template<int BKB>
__device__ __forceinline__ bf16x8 lds_frag(const unsigned short* base, int row, int kbytes) {
  int b = (row * BKB + kbytes) ^ ((row & 7) << 4);
  return *(const bf16x8*)((const char*)base + b);
}

// ---------------- embed + LN(layer0) + dual-layout emit ----------------
__global__ __launch_bounds__(512) void k_embln(
    const int* __restrict__ X, const float* __restrict__ emb,
    const float* __restrict__ lng, const float* __restrict__ lnb,
    float* __restrict__ x, unsigned short* __restrict__ xbf,
    unsigned short* __restrict__ xnT) {
  __shared__ __align__(16) float xf[16][264];
  __shared__ float mrow[16], rrow[16];
  int r0 = blockIdx.x * 16;
  int tid = threadIdx.x;
  int w = tid >> 6, lane = tid & 63;
#pragma unroll
  for (int rr = 0; rr < 2; rr++) {
    int row = w * 2 + rr; int grow = r0 + row;
    int tok = X[grow];
    f32x4 v = *(const f32x4*)(emb + (size_t)tok * D_ + lane * 4);
    *(f32x4*)(x + (size_t)grow * D_ + lane * 4) = v;
    *(f32x4*)&xf[row][lane * 4] = v;
    float s = v[0] + v[1] + v[2] + v[3];
    float ss = v[0]*v[0] + v[1]*v[1] + v[2]*v[2] + v[3]*v[3];
#pragma unroll
    for (int off = 1; off < 64; off <<= 1) {
      s  += __shfl_xor(s, off, 64);
      ss += __shfl_xor(ss, off, 64);
    }
    float mean = s * (1.f / D_);
    float var = ss * (1.f / D_) - mean * mean;
    float rinv = rsqrtf(var + 1e-5f);
    float4 g4 = *(const float4*)(lng + lane * 4);
    float4 b4 = *(const float4*)(lnb + lane * 4);
    ushort4 o;
    o.x = f2bf((v[0] - mean) * rinv * g4.x + b4.x);
    o.y = f2bf((v[1] - mean) * rinv * g4.y + b4.y);
    o.z = f2bf((v[2] - mean) * rinv * g4.z + b4.z);
    o.w = f2bf((v[3] - mean) * rinv * g4.w + b4.w);
    *(ushort4*)(xbf + (size_t)grow * D_ + lane * 4) = o;
    if (lane == 0) { mrow[row] = mean; rrow[row] = rinv; }
  }
  __syncthreads();
  int d = tid & 255, half = tid >> 8;
  float gd = lng[d], bd = lnb[d];
  int bb = r0 >> 10, s0 = r0 & 1023;
  bf16x8 o8;
#pragma unroll
  for (int k = 0; k < 8; k++) {
    int srow = half * 8 + k;
    o8[k] = (short)f2bf((xf[srow][d] - mrow[srow]) * rrow[srow] * gd + bd);
  }
  *(bf16x8*)(xnT + ((size_t)(bb * 256 + d)) * S_ + s0 + half * 8) = o8;
}

// ---------------- fused layer: MFMA attention + 3-GEMM MLP + residual + next LN ----
template<int LAST>
__global__ __launch_bounds__(512) void k_layer(
    const unsigned short* __restrict__ xbf,   // layer input  [4096][256] bf16
    const unsigned short* __restrict__ xnT,   // layer input  [4][256][1024] bf16
    const float* __restrict__ WQ, const float* __restrict__ WK,
    const float* __restrict__ WV, const float* __restrict__ Om,
    const unsigned short* __restrict__ Wl,    // 3 x [256][256] bf16 (this layer)
    const float* __restrict__ b1, const float* __restrict__ b2, const float* __restrict__ b3,
    float* __restrict__ x,                    // residual f32
    const float* __restrict__ lngN, const float* __restrict__ lnbN,
    unsigned short* __restrict__ xbfN, unsigned short* __restrict__ xnTN,  // outputs (!LAST)
    unsigned short* __restrict__ actB,        // output (LAST)
    int layer) {
  __shared__ __align__(16) unsigned short P_lds[8][16][72];
  __shared__ __align__(16) unsigned short Aa[16 * 256];
  __shared__ __align__(16) unsigned short Ab[16 * 256];
  __shared__ __align__(16) unsigned short Ab2[16 * 256];
  __shared__ __align__(16) unsigned short Bp[2][256 * 64];
  __shared__ __align__(16) float xf[16][264];
  __shared__ float mrow[16], rrow[16];

  int b = blockIdx.x >> 6;
  int q0 = (blockIdx.x & 63) << 4;
  int r0 = blockIdx.x * 16;                  // == b*S + q0
  int tid = threadIdx.x;
  int w = tid >> 6, lane = tid & 63;
  int lr = lane & 15, lg = lane >> 4;
  int h = w;

  // prefetch MLP W panel 0 (drained at the post-attention barrier)
  stage_tile_swz<256, 64, 8>(Wl, 256, Bp[0], w, lane);

  // ================= attention =================
  const float scale = 0.17677669529663687f;  // 1/sqrt(32)
  bf16x8 aq;
  {
    bf16x8 xq = *(const bf16x8*)(xbf + ((size_t)(b * S_ + q0 + lr)) * D_ + h * DH_ + lg * 8);
#pragma unroll
    for (int j = 0; j < 8; j++) {
      int dj = lg * 8 + j;
      float wq = WQ[((size_t)(layer * H_ + h)) * 1024 + dj * 33];
      float wk = WK[((size_t)(layer * H_ + h)) * 1024 + dj * 33];
      aq[j] = (short)f2bf(bf2f((unsigned short)xq[j]) * wq * wk * scale);
    }
  }
  float dvo[2];
#pragma unroll
  for (int fs = 0; fs < 2; fs++) {
    int fh = fs * 16 + lr;
    int fc = h * DH_ + fh;
    dvo[fs] = WV[((size_t)(layer * H_ + h)) * 1024 + fh * 33] *
              Om[(size_t)layer * 65536 + (size_t)fc * 257];
  }

  f32x4 accPV[2];
  accPV[0] = (f32x4){0.f, 0.f, 0.f, 0.f};
  accPV[1] = (f32x4){0.f, 0.f, 0.f, 0.f};
  float rsum[4] = {0.f, 0.f, 0.f, 0.f};

  const unsigned short* xk_base = xbf + ((size_t)b * S_) * D_ + h * DH_ + lg * 8;
  const unsigned short* vT_base = xnT + ((size_t)(b * D_ + h * DH_)) * S_;

  bf16x8 qkb[4];
#pragma unroll
  for (int c = 0; c < 4; c++)
    qkb[c] = *(const bf16x8*)(xk_base + (size_t)(c * 16 + lr) * D_);

  for (int kt = 0; kt < 16; kt++) {
    int k0 = kt * 64;
    bf16x8 pvb[2][2];
#pragma unroll
    for (int fs = 0; fs < 2; fs++)
#pragma unroll
      for (int kc = 0; kc < 2; kc++)
        pvb[fs][kc] = *(const bf16x8*)(vT_base + (size_t)(fs * 16 + lr) * S_ +
                                       k0 + kc * 32 + lg * 8);
    f32x4 s[4];
#pragma unroll
    for (int c = 0; c < 4; c++)
      s[c] = __builtin_amdgcn_mfma_f32_16x16x32_bf16(aq, qkb[c],
                (f32x4){0.f, 0.f, 0.f, 0.f}, 0, 0, 0);
    int ktn = kt < 15 ? kt + 1 : 15;
#pragma unroll
    for (int c = 0; c < 4; c++)
      qkb[c] = *(const bf16x8*)(xk_base + (size_t)(ktn * 64 + c * 16 + lr) * D_);
#pragma unroll
    for (int c = 0; c < 4; c++)
#pragma unroll
      for (int r = 0; r < 4; r++) {
        float p = __expf(s[c][r]);
        rsum[r] += p;
        P_lds[w][lg * 4 + r][c * 16 + lr] = f2bf(p);
      }
#pragma unroll
    for (int kc = 0; kc < 2; kc++) {
      bf16x8 pa = *(const bf16x8*)(&P_lds[w][lr][kc * 32 + lg * 8]);
#pragma unroll
      for (int fs = 0; fs < 2; fs++)
        accPV[fs] = __builtin_amdgcn_mfma_f32_16x16x32_bf16(pa, pvb[fs][kc],
                       accPV[fs], 0, 0, 0);
    }
  }

  float inv[4];
#pragma unroll
  for (int r = 0; r < 4; r++) {
    float v = rsum[r];
    v += __shfl_xor(v, 1, 64);
    v += __shfl_xor(v, 2, 64);
    v += __shfl_xor(v, 4, 64);
    v += __shfl_xor(v, 8, 64);
    inv[r] = 1.f / v;
  }
  // attention out -> LDS Aa (swizzled [16][256], BKB=512)
#pragma unroll
  for (int fs = 0; fs < 2; fs++)
#pragma unroll
    for (int r = 0; r < 4; r++) {
      float val = accPV[fs][r] * inv[r] * dvo[fs];
      int row = lg * 4 + r, col = h * DH_ + fs * 16 + lr;
      int byte = (row * 512 + col * 2) ^ ((row & 7) << 4);
      *(unsigned short*)((char*)Aa + byte) = f2bf(val);
    }
  __syncthreads();   // Aa visible to all waves; W panel 0 drained

  // ================= MLP: 12 panels (3 gemms x 4 k-steps), prefetch pipeline ====
  int lr16 = lr;
  f32x4 acc[2];
  acc[0] = (f32x4){0.f, 0.f, 0.f, 0.f};
  acc[1] = (f32x4){0.f, 0.f, 0.f, 0.f};
  const unsigned short* Asrc = Aa;

  for (int p = 0; p < 12; ++p) {
    if (p < 11) {
      int pn = p + 1;
      stage_tile_swz<256, 64, 8>(Wl + (size_t)(pn >> 2) * 65536 + (pn & 3) * 64,
                                 256, Bp[pn & 1], w, lane);
    }
    int kk0 = (p & 3) * 64;
#pragma unroll
    for (int kk = 0; kk < 64; kk += 32) {
      bf16x8 a = lds_frag<512>(Asrc, lr16, (kk0 + kk) * 2 + lg * 16);
#pragma unroll
      for (int j = 0; j < 2; j++) {
        bf16x8 bfg = lds_frag<128>(Bp[p & 1], w * 32 + j * 16 + lr16, kk * 2 + lg * 16);
        acc[j] = __builtin_amdgcn_mfma_f32_16x16x32_bf16(a, bfg, acc[j], 0, 0, 0);
      }
    }
    if (p == 3 || p == 7) {
      const float* bias = (p == 3) ? b1 : b2;
      unsigned short* dst = (p == 3) ? Ab : Ab2;
#pragma unroll
      for (int j = 0; j < 2; j++) {
        int col = w * 32 + j * 16 + lr16;
        float bv = bias[col];
#pragma unroll
        for (int r = 0; r < 4; r++) {
          float v = acc[j][r] + bv;
          v = 0.5f * v * (1.f + erff(v * 0.70710678118654752f));
          int row = lg * 4 + r;
          int byte = (row * 512 + col * 2) ^ ((row & 7) << 4);
          *(unsigned short*)((char*)dst + byte) = f2bf(v);
        }
      }
      acc[0] = (f32x4){0.f, 0.f, 0.f, 0.f};
      acc[1] = (f32x4){0.f, 0.f, 0.f, 0.f};
      Asrc = (p == 3) ? Ab : Ab2;
    }
    __syncthreads();
  }

  // ---- final epilogue: bias3 + residual (+ next-layer LN dual emit) ----
#pragma unroll
  for (int j = 0; j < 2; j++) {
    int col = w * 32 + j * 16 + lr16;
    float bv = b3[col];
#pragma unroll
    for (int r = 0; r < 4; r++) {
      int row = lg * 4 + r; int grow = r0 + row;
      float v = acc[j][r] + bv + x[(size_t)grow * D_ + col];
      if constexpr (LAST) {
        actB[(size_t)grow * D_ + col] = f2bf(v);
      } else {
        x[(size_t)grow * D_ + col] = v;
        xf[row][col] = v;
      }
    }
  }

  if constexpr (!LAST) {
    __syncthreads();
#pragma unroll
    for (int rr = 0; rr < 2; rr++) {
      int row = w * 2 + rr; int grow = r0 + row;
      f32x4 v = *(const f32x4*)&xf[row][lane * 4];
      float s = v[0] + v[1] + v[2] + v[3];
      float ss = v[0]*v[0] + v[1]*v[1] + v[2]*v[2] + v[3]*v[3];
#pragma unroll
      for (int off = 1; off < 64; off <<= 1) {
        s  += __shfl_xor(s, off, 64);
        ss += __shfl_xor(ss, off, 64);
      }
      float mean = s * (1.f / D_);
      float var = ss * (1.f / D_) - mean * mean;
      float rinv = rsqrtf(var + 1e-5f);
      float4 g4 = *(const float4*)(lngN + lane * 4);
      float4 b4 = *(const float4*)(lnbN + lane * 4);
      ushort4 o;
      o.x = f2bf((v[0] - mean) * rinv * g4.x + b4.x);
      o.y = f2bf((v[1] - mean) * rinv * g4.y + b4.y);
      o.z = f2bf((v[2] - mean) * rinv * g4.z + b4.z);
      o.w = f2bf((v[3] - mean) * rinv * g4.w + b4.w);
      *(ushort4*)(xbfN + (size_t)grow * D_ + lane * 4) = o;
      if (lane == 0) { mrow[row] = mean; rrow[row] = rinv; }
    }
    __syncthreads();
    int d = tid & 255, half = tid >> 8;
    float gd = lngN[d], bd = lnbN[d];
    int bb = r0 >> 10, s0 = r0 & 1023;
    bf16x8 o8;
#pragma unroll
    for (int k = 0; k < 8; k++) {
      int srow = half * 8 + k;
      o8[k] = (short)f2bf((xf[srow][d] - mrow[srow]) * rrow[srow] * gd + bd);
    }
    *(bf16x8*)(xnTN + ((size_t)(bb * 256 + d)) * S_ + s0 + half * 8) = o8;
  }
}

// ---------------- logits GEMM: B-resident persistent blocks ----------------
// 250 blocks x 512 thr (8 waves, 2x4). Block owns 128-col slab: B-panel
// (128x256, 64 KB) staged ONCE; loops 64 A-row-tiles (64x256, 32 KB,
// double-buffered, prefetch-before-compute, one barrier/iter). B traffic
// 512 MB -> 16 MB; A is L2-resident; kernel ~C-write-BW-bound (~83 us floor).
__global__ __launch_bounds__(512) void k_logits(
    const unsigned short* __restrict__ A,    // bf16 [4096][256]
    const unsigned short* __restrict__ Bt,   // bf16 [32000][256]
    float* __restrict__ C) {
  __shared__ __align__(16) unsigned short Bs[128 * 256];    // 64 KB resident
  __shared__ __align__(16) unsigned short As[2][64 * 256];  // 2 x 32 KB

  int tid = threadIdx.x, lane = tid & 63, w = tid >> 6;
  int wm = w >> 2, wn = w & 3;               // 2 (row-groups) x 4 (col-groups)
  int lr = lane & 15, lg = lane >> 4;
  int bn0 = blockIdx.x * 128;

  stage_tile_swz<128, 256, 8>(Bt + (size_t)bn0 * 256, 256, Bs, w, lane);
  stage_tile_swz<64, 256, 8>(A, 256, As[0], w, lane);
  __syncthreads();

  for (int t = 0; t < 64; ++t) {
    int cur = t & 1;
    if (t < 63)
      stage_tile_swz<64, 256, 8>(A + (size_t)(t + 1) * 64 * 256, 256, As[cur ^ 1], w, lane);

    f32x4 acc[2][2];
#pragma unroll
    for (int i = 0; i < 2; i++)
#pragma unroll
      for (int j = 0; j < 2; j++) acc[i][j] = (f32x4){0.f, 0.f, 0.f, 0.f};

#pragma unroll
    for (int ks = 0; ks < 8; ks++) {
      bf16x8 af[2], bfr[2];
#pragma unroll
      for (int i = 0; i < 2; i++)
        af[i] = lds_frag<512>(As[cur], wm * 32 + i * 16 + lr, ks * 64 + lg * 16);
#pragma unroll
      for (int j = 0; j < 2; j++)
        bfr[j] = lds_frag<512>(Bs, wn * 32 + j * 16 + lr, ks * 64 + lg * 16);
#pragma unroll
      for (int i = 0; i < 2; i++)
#pragma unroll
        for (int j = 0; j < 2; j++)
          acc[i][j] = __builtin_amdgcn_mfma_f32_16x16x32_bf16(af[i], bfr[j], acc[i][j], 0, 0, 0);
    }

    int r0 = t * 64;
#pragma unroll
    for (int i = 0; i < 2; i++)
#pragma unroll
      for (int j = 0; j < 2; j++) {
        int col = bn0 + wn * 32 + j * 16 + lr;
#pragma unroll
        for (int r = 0; r < 4; r++) {
          int row = r0 + wm * 32 + i * 16 + lg * 4 + r;
          C[(size_t)row * V_ + col] = acc[i][j][r];
        }
      }
    __syncthreads();   // next A buffer staged; prev reads done
  }
}

// ---------------- transpose + f32->bf16 convert (weights) ----------------
__device__ __forceinline__ void tconv_tile(const float* __restrict__ in,
                                           unsigned short* __restrict__ out,
                                           int R, int C, int r0, int c0, int t) {
  __shared__ float tile[64][65];
#pragma unroll
  for (int i = 0; i < 16; i++) {
    int idx = i * 256 + t;
    int lr = idx >> 6, lc = idx & 63;
    tile[lr][lc] = in[(size_t)(r0 + lr) * C + c0 + lc];
  }
  __syncthreads();
#pragma unroll
  for (int i = 0; i < 16; i++) {
    int idx = i * 256 + t;
    int lr = idx >> 6, lc = idx & 63;
    out[(size_t)(c0 + lr) * R + r0 + lc] = f2bf(tile[lc][lr]);
  }
}

__global__ __launch_bounds__(256) void k_tconv(const float* __restrict__ in,
                                               unsigned short* __restrict__ out,
                                               int R, int C) {
  tconv_tile(in, out, R, C, blockIdx.y * 64, blockIdx.x * 64, threadIdx.x);
}

__global__ __launch_bounds__(256) void k_tconv_mlp(const float* __restrict__ w1,
                                                   const float* __restrict__ w2,
                                                   const float* __restrict__ w3,
                                                   unsigned short* __restrict__ out) {
  int z = blockIdx.z; int l = z / 3, mm = z % 3;
  const float* in = (mm == 0 ? w1 : mm == 1 ? w2 : w3) + (size_t)l * 65536;
  tconv_tile(in, out + (size_t)z * 65536, 256, 256, blockIdx.y * 64, blockIdx.x * 64, threadIdx.x);
}

// ---------------- launch ----------------
extern "C" void kernel_launch(void* const* d_in, const int* in_sizes, int n_in,
                              void* d_out, int out_size, void* d_ws, size_t ws_size,
                              hipStream_t stream) {
  const int*   X      = (const int*)d_in[0];
  const float* emb    = (const float*)d_in[1];
  const float* WQ     = (const float*)d_in[2];
  const float* WK     = (const float*)d_in[3];
  const float* WV     = (const float*)d_in[4];
  const float* Om     = (const float*)d_in[5];
  const float* lng    = (const float*)d_in[6];
  const float* lnb    = (const float*)d_in[7];
  const float* w1     = (const float*)d_in[8];
  const float* b1     = (const float*)d_in[9];
  const float* w2     = (const float*)d_in[10];
  const float* b2     = (const float*)d_in[11];
  const float* w3     = (const float*)d_in[12];
  const float* b3     = (const float*)d_in[13];
  const float* logitW = (const float*)d_in[14];
  float* out = (float*)d_out;
  char* ws = (char*)d_ws;

  constexpr size_t MB = 1024u * 1024;
  float* x  = (float*)(ws);                                    // 4 MB
  unsigned short* xbf0 = (unsigned short*)(ws + 4 * MB);       // 2 MB
  unsigned short* xbf1 = (unsigned short*)(ws + 6 * MB);       // 2 MB
  unsigned short* xnT0 = (unsigned short*)(ws + 8 * MB);       // 2 MB
  unsigned short* xnT1 = (unsigned short*)(ws + 10 * MB);      // 2 MB
  unsigned short* actB = (unsigned short*)(ws + 12 * MB);      // 2 MB
  unsigned short* mlpW = (unsigned short*)(ws + 14 * MB);      // 1.5 MB
  unsigned short* lWt  = (unsigned short*)(ws + 16 * MB);      // 16 MB

  // weight conversion (bf16, transposed to [N][K])
  k_tconv_mlp<<<dim3(4, 4, 12), 256, 0, stream>>>(w1, w2, w3, mlpW);
  k_tconv<<<dim3(500, 4), 256, 0, stream>>>(logitW, lWt, 256, 32000);

  k_embln<<<256, 512, 0, stream>>>(X, emb, lng, lnb, x, xbf0, xnT0);

  for (int l = 0; l < L_; l++) {
    const unsigned short* xbfI = (l & 1) ? xbf1 : xbf0;
    const unsigned short* xnTI = (l & 1) ? xnT1 : xnT0;
    unsigned short* xbfO = (l & 1) ? xbf0 : xbf1;
    unsigned short* xnTO = (l & 1) ? xnT0 : xnT1;
    if (l < L_ - 1) {
      k_layer<0><<<256, 512, 0, stream>>>(
          xbfI, xnTI, WQ, WK, WV, Om, mlpW + (size_t)(l * 3) * 65536,
          b1 + (size_t)l * D_, b2 + (size_t)l * D_, b3 + (size_t)l * D_, x,
          lng + (size_t)(l + 1) * D_, lnb + (size_t)(l + 1) * D_,
          xbfO, xnTO, nullptr, l);
    } else {
      k_layer<1><<<256, 512, 0, stream>>>(
          xbfI, xnTI, WQ, WK, WV, Om, mlpW + (size_t)(l * 3) * 65536,
          b1 + (size_t)l * D_, b2 + (size_t)l * D_, b3 + (size_t)l * D_, x,
          nullptr, nullptr, nullptr, nullptr, actB, l);
    }
  }

  // logits: 250 persistent blocks, B-resident, A streamed through L2
  k_logits<<<250, 512, 0, stream>>>(actB, lWt, out);
}